// Round 1
// baseline (1537.668 us; speedup 1.0000x reference)
//
#include <hip/hip_runtime.h>
#include <hip/hip_bf16.h>

// GAT GNN: N=50000 nodes, E=800000 edges (+N self loops), C=64, H=4, L=3, NG=256
// Pipeline: input GEMM+relu -> 3x [xh GEMM + attn logits, per-node softmax-agg
// + LN + relu + residual] -> mean pool -> output GEMM.

__device__ __forceinline__ float wave_sum(float v) {
#pragma unroll
  for (int d = 32; d > 0; d >>= 1) v += __shfl_xor(v, d, 64);
  return v;
}

__device__ __forceinline__ float lrelu02(float v) { return v > 0.f ? v : 0.2f * v; }

// h = relu(x @ W_in + b_in); x [N,32], W_in [32,64] -> h [N,64]. One wave/node.
__global__ __launch_bounds__(256) void k_input(const float* __restrict__ x,
    const float* __restrict__ Win, const float* __restrict__ bin,
    float* __restrict__ h, int N)
{
  int n = (blockIdx.x * 256 + threadIdx.x) >> 6;
  int lane = threadIdx.x & 63;
  if (n >= N) return;
  float xv = (lane < 32) ? x[n * 32 + lane] : 0.f;
  float acc = bin[lane];
#pragma unroll
  for (int k = 0; k < 32; ++k)
    acc = fmaf(__shfl(xv, k, 64), Win[k * 64 + lane], acc);
  h[n * 64 + lane] = fmaxf(acc, 0.f);
}

__global__ void k_set1(int* __restrict__ p, int n) {
  int t = blockIdx.x * blockDim.x + threadIdx.x;
  if (t < n) p[t] = 1;
}

__global__ void k_count(const int* __restrict__ dst, int* __restrict__ cnt, int E) {
  int t = blockIdx.x * blockDim.x + threadIdx.x;
  if (t < E) atomicAdd(&cnt[dst[t]], 1);
}

// Single-block exclusive scan of counter[0..N) -> rowstart[0..N]; also writes
// exclusive value back into counter[] (used as running fill cursor).
__global__ __launch_bounds__(1024) void k_scan(int* __restrict__ counter,
                                               int* __restrict__ rowstart, int N)
{
  __shared__ int wsums[16];
  __shared__ int s_carry;
  int tid = threadIdx.x, lane = tid & 63, wid = tid >> 6;
  if (tid == 0) s_carry = 0;
  __syncthreads();
  for (int base = 0; base < N; base += 1024) {
    int i = base + tid;
    int v = (i < N) ? counter[i] : 0;
    int x = v;
#pragma unroll
    for (int d = 1; d < 64; d <<= 1) {
      int y = __shfl_up(x, d, 64);
      if (lane >= d) x += y;
    }
    if (lane == 63) wsums[wid] = x;
    __syncthreads();
    if (wid == 0) {
      int s = (lane < 16) ? wsums[lane] : 0;
#pragma unroll
      for (int d = 1; d < 16; d <<= 1) {
        int y = __shfl_up(s, d, 64);
        if (lane >= d) s += y;
      }
      if (lane < 16) wsums[lane] = s;
    }
    __syncthreads();
    int carry = s_carry;
    int woff = (wid > 0) ? wsums[wid - 1] : 0;
    int excl = carry + woff + (x - v);
    if (i < N) { rowstart[i] = excl; counter[i] = excl; }
    int total = wsums[15];
    __syncthreads();
    if (tid == 0) s_carry = carry + total;
    __syncthreads();
  }
  if (threadIdx.x == 0) rowstart[N] = s_carry;
}

// Scatter edges (incl. self loops) into dst-grouped order: srcs[pos] = src.
__global__ void k_fill(const int* __restrict__ src, const int* __restrict__ dst,
                       int* __restrict__ counter, int* __restrict__ srcs, int E, int N)
{
  int t = blockIdx.x * blockDim.x + threadIdx.x;
  if (t >= E + N) return;
  int s, d;
  if (t < E) { s = src[t]; d = dst[t]; } else { s = t - E; d = s; }
  int pos = atomicAdd(&counter[d], 1);
  srcs[pos] = s;
}

// xh[n,256] = h[n,:] @ Wg[64,256]; al_s/al_d[n,h] = sum_c xh[n,h,c]*att[h,c].
// Thread tid owns output column tid; W column cached in 64 VGPRs; h[n]
// broadcast via __shfl. Wave wid == head wid for the al reduction.
__global__ __launch_bounds__(256) void k_xh(const float* __restrict__ h,
    const float* __restrict__ Wg, const float* __restrict__ asrc,
    const float* __restrict__ adst, float* __restrict__ xh,
    float* __restrict__ als, float* __restrict__ ald, int N)
{
  int tid = threadIdx.x;
  int lane = tid & 63, wid = tid >> 6;
  float wreg[64];
#pragma unroll
  for (int k = 0; k < 64; ++k) wreg[k] = Wg[k * 256 + tid];
  float avs = asrc[tid], avd = adst[tid];
  int n0 = blockIdx.x * 64;
  int nend = n0 + 64 < N ? n0 + 64 : N;
  for (int n = n0; n < nend; ++n) {
    float hv = h[n * 64 + lane];
    float acc = 0.f;
#pragma unroll
    for (int k = 0; k < 64; ++k)
      acc = fmaf(__shfl(hv, k, 64), wreg[k], acc);
    xh[(size_t)n * 256 + tid] = acc;
    float ps = wave_sum(acc * avs);
    float pd = wave_sum(acc * avd);
    if (lane == 0) { als[n * 4 + wid] = ps; ald[n * 4 + wid] = pd; }
  }
}

// One wave per node: two-pass softmax over incoming edges + weighted aggregate
// of xh[src], head-mean, bias, LayerNorm, relu, residual (in-place on h).
__global__ __launch_bounds__(256) void k_agg(const float* __restrict__ xh,
    const float* __restrict__ als, const float* __restrict__ ald,
    const int* __restrict__ rowstart, const int* __restrict__ srcs,
    const float* __restrict__ bias, const float* __restrict__ g,
    const float* __restrict__ b, float* __restrict__ h, int N, int doRes)
{
  int n = (blockIdx.x * 256 + threadIdx.x) >> 6;
  int lane = threadIdx.x & 63;
  if (n >= N) return;
  int beg = rowstart[n], end = rowstart[n + 1];
  float ad0 = ald[n * 4 + 0], ad1 = ald[n * 4 + 1];
  float ad2 = ald[n * 4 + 2], ad3 = ald[n * 4 + 3];
  float m0 = -1e30f, m1 = -1e30f, m2 = -1e30f, m3 = -1e30f;
  for (int i = beg; i < end; ++i) {
    int s = srcs[i];
    m0 = fmaxf(m0, lrelu02(als[s * 4 + 0] + ad0));
    m1 = fmaxf(m1, lrelu02(als[s * 4 + 1] + ad1));
    m2 = fmaxf(m2, lrelu02(als[s * 4 + 2] + ad2));
    m3 = fmaxf(m3, lrelu02(als[s * 4 + 3] + ad3));
  }
  float l0 = 0, l1 = 0, l2 = 0, l3 = 0;
  float a0 = 0, a1 = 0, a2 = 0, a3 = 0;
  for (int i = beg; i < end; ++i) {
    int s = srcs[i];
    float p0 = __expf(lrelu02(als[s * 4 + 0] + ad0) - m0);
    float p1 = __expf(lrelu02(als[s * 4 + 1] + ad1) - m1);
    float p2 = __expf(lrelu02(als[s * 4 + 2] + ad2) - m2);
    float p3 = __expf(lrelu02(als[s * 4 + 3] + ad3) - m3);
    l0 += p0; l1 += p1; l2 += p2; l3 += p3;
    const float* xs = xh + (size_t)s * 256;
    a0 = fmaf(p0, xs[lane], a0);
    a1 = fmaf(p1, xs[64 + lane], a1);
    a2 = fmaf(p2, xs[128 + lane], a2);
    a3 = fmaf(p3, xs[192 + lane], a3);
  }
  float o = 0.25f * (a0 / (l0 + 1e-16f) + a1 / (l1 + 1e-16f) +
                     a2 / (l2 + 1e-16f) + a3 / (l3 + 1e-16f)) + bias[lane];
  float mu = wave_sum(o) * 0.015625f;
  float dv = o - mu;
  float var = wave_sum(dv * dv) * 0.015625f;
  float y = dv * rsqrtf(var + 1e-5f) * g[lane] + b[lane];
  float r = fmaxf(y, 0.f);
  if (doRes) r += h[n * 64 + lane];
  h[n * 64 + lane] = r;
}

__global__ void k_zero(float* __restrict__ p, int n) {
  int t = blockIdx.x * blockDim.x + threadIdx.x;
  if (t < n) p[t] = 0.f;
}

__global__ void k_pool(const float* __restrict__ h, const int* __restrict__ batch,
                       float* __restrict__ pool, float* __restrict__ cnt, int N)
{
  int t = blockIdx.x * blockDim.x + threadIdx.x;
  if (t >= N * 64) return;
  int n = t >> 6, c = t & 63;
  int gid = batch[n];
  atomicAdd(&pool[gid * 64 + c], h[t]);
  if (c == 0) atomicAdd(&cnt[gid], 1.f);
}

__global__ void k_out(const float* __restrict__ pool, const float* __restrict__ cnt,
                      const float* __restrict__ Wout, const float* __restrict__ bout,
                      float* __restrict__ out, int NG)
{
  int t = blockIdx.x * blockDim.x + threadIdx.x;
  if (t >= NG * 32) return;
  int gid = t >> 5, j = t & 31;
  float s = 0.f;
#pragma unroll
  for (int c = 0; c < 64; ++c) s = fmaf(pool[gid * 64 + c], Wout[c * 32 + j], s);
  out[t] = s / fmaxf(cnt[gid], 1.f) + bout[j];
}

extern "C" void kernel_launch(void* const* d_in, const int* in_sizes, int n_in,
                              void* d_out, int out_size, void* d_ws, size_t ws_size,
                              hipStream_t stream) {
  const float* x    = (const float*)d_in[0];
  const int*   ei   = (const int*)d_in[1];
  const int*   batch= (const int*)d_in[2];
  const float* Win  = (const float*)d_in[3];
  const float* bin  = (const float*)d_in[4];
  const float* Wgat = (const float*)d_in[5];
  const float* asrc = (const float*)d_in[6];
  const float* adst = (const float*)d_in[7];
  const float* bgat = (const float*)d_in[8];
  const float* lng  = (const float*)d_in[9];
  const float* lnb  = (const float*)d_in[10];
  const float* Wout = (const float*)d_in[11];
  const float* bout = (const float*)d_in[12];
  float* out = (float*)d_out;

  int N  = in_sizes[0] / 32;
  int E  = in_sizes[1] / 2;
  int NG = out_size / 32;
  int L  = in_sizes[5] / (64 * 256);

  char* w = (char*)d_ws;
  float* xh = (float*)w;       w += (size_t)N * 256 * 4;
  float* h  = (float*)w;       w += (size_t)N * 64 * 4;
  float* als= (float*)w;       w += (size_t)N * 4 * 4;
  float* ald= (float*)w;       w += (size_t)N * 4 * 4;
  int* rowstart = (int*)w;     w += (size_t)(N + 1) * 4;
  int* counter  = (int*)w;     w += (size_t)N * 4;
  int* srcs     = (int*)w;     w += (size_t)(E + N) * 4;
  float* pool   = (float*)w;   w += (size_t)NG * 64 * 4;
  float* cnt    = (float*)w;   w += (size_t)NG * 4;

  const int* esrc = ei;       // edge_index[0]
  const int* edst = ei + E;   // edge_index[1]

  // input layer
  k_input<<<(N + 3) / 4, 256, 0, stream>>>(x, Win, bin, h, N);

  // CSR build (dst-grouped), self-loops included via deg init = 1
  k_set1<<<(N + 255) / 256, 256, 0, stream>>>(counter, N);
  k_count<<<(E + 255) / 256, 256, 0, stream>>>(edst, counter, E);
  k_scan<<<1, 1024, 0, stream>>>(counter, rowstart, N);
  k_fill<<<(E + N + 255) / 256, 256, 0, stream>>>(esrc, edst, counter, srcs, E, N);

  for (int i = 0; i < L; ++i) {
    k_xh<<<(N + 63) / 64, 256, 0, stream>>>(h, Wgat + (size_t)i * 64 * 256,
        asrc + i * 256, adst + i * 256, xh, als, ald, N);
    k_agg<<<(N + 3) / 4, 256, 0, stream>>>(xh, als, ald, rowstart, srcs,
        bgat + i * 64, lng + i * 64, lnb + i * 64, h, N, i > 0 ? 1 : 0);
  }

  // mean pool + output GEMM
  k_zero<<<(NG * 65 + 255) / 256, 256, 0, stream>>>(pool, NG * 65); // pool then cnt (contiguous)
  k_pool<<<(N * 64 + 255) / 256, 256, 0, stream>>>(h, batch, pool, cnt, N);
  k_out<<<(NG * 32 + 255) / 256, 256, 0, stream>>>(pool, cnt, Wout, bout, out, NG);
}